// Round 3
// baseline (2261.862 us; speedup 1.0000x reference)
//
#include <hip/hip_runtime.h>

#define N_NODES 100000
#define N_EDGES 3200000
#define N_GRAPHS 2048

// ---------- degree (includes +1 self-loop analytically) ----------
__global__ void k_deg(const int* __restrict__ dst, int* __restrict__ deg) {
  int e = blockIdx.x * 256 + threadIdx.x;
  if (e < N_EDGES) atomicAdd(&deg[dst[e]], 1);
}

// dinv, xd = x*dinv (5-dim gather table), s1 pre-seeded with self-loop term,
// and per-graph node counts
__global__ void k_prep(const float* __restrict__ x, const int* __restrict__ deg,
                       const int* __restrict__ batch, float* __restrict__ dinv,
                       float* __restrict__ xd, float* __restrict__ s1,
                       int* __restrict__ gcnt) {
  int i = blockIdx.x * 256 + threadIdx.x;
  if (i >= N_NODES) return;
  float di = rsqrtf((float)(deg[i] + 1));   // deg+1 >= 1 always
  dinv[i] = di;
  atomicAdd(&gcnt[batch[i]], 1);            // wave-coalesced (batch sorted)
#pragma unroll
  for (int c = 0; c < 5; c++) {
    float v = x[i * 5 + c] * di;
    xd[i * 5 + c] = v;
    s1[i * 5 + c] = v;                      // self-loop contribution
  }
}

// layer-1 scatter: s1[d] += xd[s]  (gather table 2MB, acc 2MB — both L2-resident)
__global__ void k_sc1(const int* __restrict__ src, const int* __restrict__ dst,
                      const float* __restrict__ xd, float* __restrict__ s1) {
  int e = blockIdx.x * 256 + threadIdx.x;
  if (e >= N_EDGES) return;
  int s = src[e], d = dst[e];
#pragma unroll
  for (int c = 0; c < 5; c++)
    atomicAdd(&s1[d * 5 + c], xd[s * 5 + c]);
}

// fused per-node MLP: t = dinv*s1; h = relu(t@W1 + b1); g2 = (h@W2)*dinv
// s2 pre-seeded with self-loop term. a1/g1 never materialized.
__global__ void k_mlp(const float* __restrict__ s1, const float* __restrict__ dinv,
                      const float* __restrict__ W1, const float* __restrict__ b1,
                      const float* __restrict__ W2,
                      float* __restrict__ g2, float* __restrict__ s2) {
  __shared__ float w1[150], bb1[30], w2[240];
  int tid = threadIdx.x;
  for (int i = tid; i < 150; i += 256) w1[i] = W1[i];
  for (int i = tid; i < 30; i += 256) bb1[i] = b1[i];
  for (int i = tid; i < 240; i += 256) w2[i] = W2[i];
  __syncthreads();
  int i = blockIdx.x * 256 + tid;
  if (i >= N_NODES) return;
  float di = dinv[i];
  float t[5];
#pragma unroll
  for (int c = 0; c < 5; c++) t[c] = s1[i * 5 + c] * di;
  float h[30];
#pragma unroll
  for (int j = 0; j < 30; j++) h[j] = bb1[j];
#pragma unroll
  for (int k = 0; k < 5; k++)
#pragma unroll
    for (int j = 0; j < 30; j++) h[j] += t[k] * w1[k * 30 + j];
#pragma unroll
  for (int j = 0; j < 30; j++) h[j] = fmaxf(h[j], 0.f);
  float g[8];
#pragma unroll
  for (int c = 0; c < 8; c++) g[c] = 0.f;
#pragma unroll
  for (int j = 0; j < 30; j++)
#pragma unroll
    for (int c = 0; c < 8; c++) g[c] += h[j] * w2[j * 8 + c];
#pragma unroll
  for (int c = 0; c < 8; c++) g[c] *= di;
  float4 lo = make_float4(g[0], g[1], g[2], g[3]);
  float4 hi = make_float4(g[4], g[5], g[6], g[7]);
  ((float4*)g2)[i * 2] = lo;
  ((float4*)g2)[i * 2 + 1] = hi;
  ((float4*)s2)[i * 2] = lo;                // self-loop contribution
  ((float4*)s2)[i * 2 + 1] = hi;
}

// layer-2 scatter: s2[d] += g2[s]  (table 3.2MB, acc 3.2MB — L2-resident)
__global__ void k_sc2(const int* __restrict__ src, const int* __restrict__ dst,
                      const float* __restrict__ g2, float* __restrict__ s2) {
  int e = blockIdx.x * 256 + threadIdx.x;
  if (e >= N_EDGES) return;
  int s = src[e], d = dst[e];
  const float4* gv = (const float4*)g2;
  float4 lo = gv[s * 2], hi = gv[s * 2 + 1];
  float* p = s2 + (size_t)d * 8;
  atomicAdd(p + 0, lo.x); atomicAdd(p + 1, lo.y);
  atomicAdd(p + 2, lo.z); atomicAdd(p + 3, lo.w);
  atomicAdd(p + 4, hi.x); atomicAdd(p + 5, hi.y);
  atomicAdd(p + 6, hi.z); atomicAdd(p + 7, hi.w);
}

// per-node epilogue + graph-sum pooling
__global__ void k_out(const float* __restrict__ s2, const float* __restrict__ dinv,
                      const float* __restrict__ b2, const int* __restrict__ batch,
                      float* __restrict__ gsum) {
  int t = blockIdx.x * 256 + threadIdx.x;
  if (t >= N_NODES * 8) return;
  int n = t >> 3, c = t & 7;
  float v = dinv[n] * s2[t] + b2[c];
  atomicAdd(&gsum[batch[n] * 8 + c], v);
}

__global__ void k_final(const float* __restrict__ gsum, const int* __restrict__ gcnt,
                        float* __restrict__ out) {
  int i = blockIdx.x * 256 + threadIdx.x;
  if (i < N_GRAPHS * 8) {
    float c = (float)gcnt[i >> 3];
    out[i] = gsum[i] / fmaxf(c, 1.f);
  }
}

extern "C" void kernel_launch(void* const* d_in, const int* in_sizes, int n_in,
                              void* d_out, int out_size, void* d_ws, size_t ws_size,
                              hipStream_t stream) {
  const float* x    = (const float*)d_in[0];
  const int* ei     = (const int*)d_in[1];
  const int* batch  = (const int*)d_in[2];
  const float* W1   = (const float*)d_in[3];
  const float* b1   = (const float*)d_in[4];
  const float* W2   = (const float*)d_in[5];
  const float* b2   = (const float*)d_in[6];
  const int* srcp = ei;
  const int* dstp = ei + N_EDGES;
  float* out = (float*)d_out;

  // workspace carve (~11.3 MB)
  char* base = (char*)d_ws;
  size_t o = 0;
  auto carve = [&](size_t bytes) -> char* {
    char* p = base + o;
    o += (bytes + 255) & ~(size_t)255;
    return p;
  };
  int* deg    = (int*)carve((size_t)N_NODES * 4);
  float* dinv = (float*)carve((size_t)N_NODES * 4);
  float* xd   = (float*)carve((size_t)N_NODES * 5 * 4);
  float* s1   = (float*)carve((size_t)N_NODES * 5 * 4);
  float* g2   = (float*)carve((size_t)N_NODES * 8 * 4);
  float* s2   = (float*)carve((size_t)N_NODES * 8 * 4);
  float* gsum = (float*)carve((size_t)N_GRAPHS * 8 * 4);
  int* gcnt   = (int*)carve((size_t)N_GRAPHS * 4);

  hipMemsetAsync(deg, 0, (size_t)N_NODES * 4, stream);
  hipMemsetAsync(gsum, 0, (size_t)N_GRAPHS * 8 * 4, stream);
  hipMemsetAsync(gcnt, 0, (size_t)N_GRAPHS * 4, stream);

  int nb_e = (N_EDGES + 255) / 256;
  int nb_n = (N_NODES + 255) / 256;

  k_deg<<<nb_e, 256, 0, stream>>>(dstp, deg);
  k_prep<<<nb_n, 256, 0, stream>>>(x, deg, batch, dinv, xd, s1, gcnt);
  k_sc1<<<nb_e, 256, 0, stream>>>(srcp, dstp, xd, s1);
  k_mlp<<<nb_n, 256, 0, stream>>>(s1, dinv, W1, b1, W2, g2, s2);
  k_sc2<<<nb_e, 256, 0, stream>>>(srcp, dstp, g2, s2);
  k_out<<<(N_NODES * 8 + 255) / 256, 256, 0, stream>>>(s2, dinv, b2, batch, gsum);
  k_final<<<(N_GRAPHS * 8 + 255) / 256, 256, 0, stream>>>(gsum, gcnt, out);
}

// Round 4
// 391.930 us; speedup vs baseline: 5.7711x; 5.7711x over previous
//
#include <hip/hip_runtime.h>

#define N_NODES 100000
#define N_EDGES 3200000
#define N_GRAPHS 2048
#define BSH 8                       // 256 nodes per bucket
#define BSZ 256
#define NB 391                      // ceil(N_NODES/256)
#define FILL_BLOCKS 512
#define CHUNK 6250                  // N_EDGES / FILL_BLOCKS exactly

__device__ __forceinline__ void atomAddF(float* p, float v) {
#if defined(__gfx90a__) || defined(__gfx940__) || defined(__gfx941__) || defined(__gfx942__) || defined(__gfx950__)
  unsafeAtomicAdd(p, v);
#else
  atomicAdd(p, v);
#endif
}

// ---------- pass 1: per-block bucket histogram + space reservation ----------
__global__ void k_count(const int* __restrict__ dst, int* __restrict__ bcnt,
                        int* __restrict__ blockBase) {
  __shared__ int hist[NB];
  int tid = threadIdx.x, blk = blockIdx.x;
  for (int i = tid; i < NB; i += 256) hist[i] = 0;
  __syncthreads();
  int beg = blk * CHUNK, end = beg + CHUNK;
  for (int e = beg + tid; e < end; e += 256) atomicAdd(&hist[dst[e] >> BSH], 1);
  __syncthreads();
  for (int i = tid; i < NB; i += 256) {
    int h = hist[i];
    if (h) blockBase[blk * NB + i] = atomicAdd(&bcnt[i], h);
  }
}

// ---------- exclusive scan over NB bucket counts (single block) ----------
__global__ void k_bscan(const int* __restrict__ bcnt, int* __restrict__ boffs) {
  __shared__ int sh[512];
  int tid = threadIdx.x;
  int v = (tid < NB) ? bcnt[tid] : 0;
  sh[tid] = v;
  __syncthreads();
  for (int off = 1; off < 512; off <<= 1) {
    int t = (tid >= off) ? sh[tid - off] : 0;
    __syncthreads();
    sh[tid] += t;
    __syncthreads();
  }
  if (tid < NB) boffs[tid] = sh[tid] - v;
  if (tid == 0) boffs[NB] = N_EDGES;
}

// ---------- pass 2: write packed edges into reserved dense sub-ranges ----------
__global__ void k_fill(const int* __restrict__ src, const int* __restrict__ dst,
                       const int* __restrict__ boffs, const int* __restrict__ blockBase,
                       unsigned* __restrict__ stage) {
  __shared__ int lbase[NB];
  int tid = threadIdx.x, blk = blockIdx.x;
  for (int i = tid; i < NB; i += 256) lbase[i] = boffs[i] + blockBase[blk * NB + i];
  __syncthreads();
  int beg = blk * CHUNK, end = beg + CHUNK;
  for (int e = beg + tid; e < end; e += 256) {
    int d = dst[e], s = src[e];
    int pos = atomicAdd(&lbase[d >> BSH], 1);   // LDS cursor
    stage[pos] = ((unsigned)s << BSH) | (unsigned)(d & (BSZ - 1));
  }
}

// ---------- bucket-local degree -> dinv, xd = x*dinv, graph node counts ----------
__global__ void k_prep(const unsigned* __restrict__ stage, const int* __restrict__ boffs,
                       const float* __restrict__ x, const int* __restrict__ batch,
                       float* __restrict__ dinv, float* __restrict__ xd,
                       int* __restrict__ gcnt) {
  __shared__ int cnt[BSZ];
  int b = blockIdx.x, tid = threadIdx.x;
  cnt[tid] = 0;
  __syncthreads();
  int beg = boffs[b], end = boffs[b + 1];
  for (int k = beg + tid; k < end; k += 256) atomicAdd(&cnt[stage[k] & (BSZ - 1)], 1);
  __syncthreads();
  int node = b * BSZ + tid;
  if (node < N_NODES) {
    float di = rsqrtf((float)(cnt[tid] + 1));     // +1 self-loop; always > 0
    dinv[node] = di;
#pragma unroll
    for (int c = 0; c < 5; c++) xd[node * 5 + c] = x[node * 5 + c] * di;
    atomicAdd(&gcnt[batch[node]], 1);
  }
}

// ---------- layer-1 aggregation (5-dim, table L2-resident) + fused MLP ----------
// out: g2 = (relu((dinv*(xd[d]+sum xd[s]))@W1 + b1)@W2) * dinv
__global__ void k_agg1(const unsigned* __restrict__ stage, const int* __restrict__ boffs,
                       const float* __restrict__ xd, const float* __restrict__ dinv,
                       const float* __restrict__ W1, const float* __restrict__ b1,
                       const float* __restrict__ W2, float* __restrict__ g2) {
  __shared__ float acc[BSZ * 5];
  __shared__ float w1[150], bb1[30], w2[240];
  int b = blockIdx.x, tid = threadIdx.x;
  for (int i = tid; i < BSZ * 5; i += 256) acc[i] = 0.f;
  for (int i = tid; i < 150; i += 256) w1[i] = W1[i];
  for (int i = tid; i < 30; i += 256) bb1[i] = b1[i];
  for (int i = tid; i < 240; i += 256) w2[i] = W2[i];
  __syncthreads();
  int beg = boffs[b], end = boffs[b + 1];
  int group = tid / 5, lane = tid - group * 5;    // 51 groups x 5 lanes, tid 255 idle
  if (tid < 255) {
    for (int k = beg + group; k < end; k += 51) {
      unsigned v = stage[k];
      int s = v >> BSH, l = v & (BSZ - 1);
      atomAddF(&acc[l * 5 + lane], xd[s * 5 + lane]);
    }
  }
  __syncthreads();
  int node = b * BSZ + tid;
  if (node < N_NODES) {
    float di = dinv[node];
    float t[5];
#pragma unroll
    for (int c = 0; c < 5; c++) t[c] = (acc[tid * 5 + c] + xd[node * 5 + c]) * di;
    float h[30];
#pragma unroll
    for (int j = 0; j < 30; j++) h[j] = bb1[j];
#pragma unroll
    for (int k = 0; k < 5; k++)
#pragma unroll
      for (int j = 0; j < 30; j++) h[j] += t[k] * w1[k * 30 + j];
    float g[8] = {0, 0, 0, 0, 0, 0, 0, 0};
#pragma unroll
    for (int j = 0; j < 30; j++) {
      float hj = fmaxf(h[j], 0.f);
#pragma unroll
      for (int c = 0; c < 8; c++) g[c] += hj * w2[j * 8 + c];
    }
    float4* gv = (float4*)g2;
    gv[node * 2]     = make_float4(g[0] * di, g[1] * di, g[2] * di, g[3] * di);
    gv[node * 2 + 1] = make_float4(g[4] * di, g[5] * di, g[6] * di, g[7] * di);
  }
}

// ---------- layer-2 aggregation (8-dim, table L2-resident) + fused pooling ----------
__global__ void k_agg2(const unsigned* __restrict__ stage, const int* __restrict__ boffs,
                       const float* __restrict__ g2, const float* __restrict__ dinv,
                       const float* __restrict__ b2, const int* __restrict__ batch,
                       float* __restrict__ gsum) {
  __shared__ float acc[BSZ * 8];
  __shared__ float gpool[32 * 8];
  __shared__ float bb2[8];
  __shared__ int batch0s;
  int b = blockIdx.x, tid = threadIdx.x;
  for (int i = tid; i < BSZ * 8; i += 256) acc[i] = 0.f;
  if (tid < 256) { if (tid < 32 * 8) gpool[tid] = 0.f; }
  if (tid < 8) bb2[tid] = b2[tid];
  if (tid == 0) batch0s = batch[b * BSZ];
  __syncthreads();
  int beg = boffs[b], end = boffs[b + 1];
  int group = tid >> 3, lane = tid & 7;           // 32 groups x 8 lanes
  for (int k = beg + group; k < end; k += 32) {
    unsigned v = stage[k];
    int s = v >> BSH, l = v & (BSZ - 1);
    atomAddF(&acc[l * 8 + lane], g2[s * 8 + lane]);
  }
  __syncthreads();
  int node = b * BSZ + tid;
  int batch0 = batch0s;
  if (node < N_NODES) {
    float di = dinv[node];
    int goff = batch[node] - batch0;
#pragma unroll
    for (int c = 0; c < 8; c++) {
      float val = di * (g2[node * 8 + c] + acc[tid * 8 + c]) + bb2[c];
      if (goff < 32) atomAddF(&gpool[goff * 8 + c], val);
      else           atomAddF(&gsum[batch[node] * 8 + c], val);
    }
  }
  __syncthreads();
  // one thread per gpool slot
  int gid = batch0 + (tid >> 3);
  float v = gpool[tid];
  if (gid < N_GRAPHS && v != 0.f) atomAddF(&gsum[gid * 8 + (tid & 7)], v);
}

__global__ void k_final(const float* __restrict__ gsum, const int* __restrict__ gcnt,
                        float* __restrict__ out) {
  int i = blockIdx.x * 256 + threadIdx.x;
  if (i < N_GRAPHS * 8) {
    float c = (float)gcnt[i >> 3];
    out[i] = gsum[i] / fmaxf(c, 1.f);
  }
}

extern "C" void kernel_launch(void* const* d_in, const int* in_sizes, int n_in,
                              void* d_out, int out_size, void* d_ws, size_t ws_size,
                              hipStream_t stream) {
  const float* x    = (const float*)d_in[0];
  const int* ei     = (const int*)d_in[1];
  const int* batch  = (const int*)d_in[2];
  const float* W1   = (const float*)d_in[3];
  const float* b1   = (const float*)d_in[4];
  const float* W2   = (const float*)d_in[5];
  const float* b2   = (const float*)d_in[6];
  const int* srcp = ei;
  const int* dstp = ei + N_EDGES;
  float* out = (float*)d_out;

  // workspace carve (~19.5 MB)
  char* base = (char*)d_ws;
  size_t o = 0;
  auto carve = [&](size_t bytes) -> char* {
    char* p = base + o;
    o += (bytes + 255) & ~(size_t)255;
    return p;
  };
  int* bcnt       = (int*)carve((size_t)NB * 4);
  int* boffs      = (int*)carve((size_t)(NB + 1) * 4);
  int* blockBase  = (int*)carve((size_t)FILL_BLOCKS * NB * 4);
  unsigned* stage = (unsigned*)carve((size_t)N_EDGES * 4);
  float* dinv     = (float*)carve((size_t)N_NODES * 4);
  float* xd       = (float*)carve((size_t)N_NODES * 5 * 4);
  float* g2       = (float*)carve((size_t)N_NODES * 8 * 4);
  float* gsum     = (float*)carve((size_t)N_GRAPHS * 8 * 4);
  int* gcnt       = (int*)carve((size_t)N_GRAPHS * 4);

  hipMemsetAsync(bcnt, 0, (size_t)NB * 4, stream);
  hipMemsetAsync(gsum, 0, (size_t)N_GRAPHS * 8 * 4, stream);
  hipMemsetAsync(gcnt, 0, (size_t)N_GRAPHS * 4, stream);

  k_count<<<FILL_BLOCKS, 256, 0, stream>>>(dstp, bcnt, blockBase);
  k_bscan<<<1, 512, 0, stream>>>(bcnt, boffs);
  k_fill<<<FILL_BLOCKS, 256, 0, stream>>>(srcp, dstp, boffs, blockBase, stage);
  k_prep<<<NB, 256, 0, stream>>>(stage, boffs, x, batch, dinv, xd, gcnt);
  k_agg1<<<NB, 256, 0, stream>>>(stage, boffs, xd, dinv, W1, b1, W2, g2);
  k_agg2<<<NB, 256, 0, stream>>>(stage, boffs, g2, dinv, b2, batch, gsum);
  k_final<<<64, 256, 0, stream>>>(gsum, gcnt, out);
}

// Round 5
// 352.446 us; speedup vs baseline: 6.4176x; 1.1120x over previous
//
#include <hip/hip_runtime.h>

#define N_NODES 100000
#define N_EDGES 3200000
#define N_GRAPHS 2048
#define BSH 6                       // 64 nodes per bucket
#define BSZ 64
#define NB 1563                     // ceil(N_NODES/64)
#define FILL_BLOCKS 512
#define CHUNK 6250                  // N_EDGES / FILL_BLOCKS exactly

__device__ __forceinline__ void atomAddF(float* p, float v) {
#if defined(__gfx90a__) || defined(__gfx940__) || defined(__gfx941__) || defined(__gfx942__) || defined(__gfx950__)
  unsafeAtomicAdd(p, v);
#else
  atomicAdd(p, v);
#endif
}

// ---------- pass 1: per-block bucket histogram + space reservation ----------
__global__ void k_count(const int* __restrict__ dst, int* __restrict__ bcnt,
                        int* __restrict__ blockBase) {
  __shared__ int hist[NB];
  int tid = threadIdx.x, blk = blockIdx.x;
  for (int i = tid; i < NB; i += 256) hist[i] = 0;
  __syncthreads();
  int beg = blk * CHUNK, end = beg + CHUNK;
  for (int e = beg + tid; e < end; e += 256) atomicAdd(&hist[dst[e] >> BSH], 1);
  __syncthreads();
  for (int i = tid; i < NB; i += 256) {
    int h = hist[i];
    if (h) blockBase[blk * NB + i] = atomicAdd(&bcnt[i], h);
  }
}

// ---------- exclusive scan over NB bucket counts (single block, chunked) ----------
__global__ void k_bscan(const int* __restrict__ bcnt, int* __restrict__ boffs) {
  __shared__ int sh[512];
  __shared__ int carry;
  int tid = threadIdx.x;
  if (tid == 0) carry = 0;
  __syncthreads();
  for (int c = 0; c < NB; c += 512) {
    int i = c + tid;
    int v = (i < NB) ? bcnt[i] : 0;
    sh[tid] = v;
    __syncthreads();
    for (int off = 1; off < 512; off <<= 1) {
      int t = (tid >= off) ? sh[tid - off] : 0;
      __syncthreads();
      sh[tid] += t;
      __syncthreads();
    }
    if (i < NB) boffs[i] = carry + sh[tid] - v;
    __syncthreads();
    if (tid == 511) carry += sh[511];
    __syncthreads();
  }
  if (tid == 0) boffs[NB] = N_EDGES;
}

// ---------- pass 2: write packed edges into reserved dense sub-ranges ----------
__global__ void k_fill(const int* __restrict__ src, const int* __restrict__ dst,
                       const int* __restrict__ boffs, const int* __restrict__ blockBase,
                       unsigned* __restrict__ stage) {
  __shared__ int lbase[NB];
  int tid = threadIdx.x, blk = blockIdx.x;
  for (int i = tid; i < NB; i += 256) lbase[i] = boffs[i] + blockBase[blk * NB + i];
  __syncthreads();
  int beg = blk * CHUNK, end = beg + CHUNK;
  for (int e = beg + tid; e < end; e += 256) {
    int d = dst[e], s = src[e];
    int pos = atomicAdd(&lbase[d >> BSH], 1);   // LDS cursor
    stage[pos] = ((unsigned)s << BSH) | (unsigned)(d & (BSZ - 1));
  }
}

// ---------- bucket-local degree -> dinv, xd = x*dinv ----------
__global__ void k_prep(const unsigned* __restrict__ stage, const int* __restrict__ boffs,
                       const float* __restrict__ x, float* __restrict__ dinv,
                       float* __restrict__ xd) {
  __shared__ int cnt[BSZ];
  int b = blockIdx.x, tid = threadIdx.x;
  if (tid < BSZ) cnt[tid] = 0;
  __syncthreads();
  int beg = boffs[b], end = boffs[b + 1];
  for (int k = beg + tid; k < end; k += 256) atomicAdd(&cnt[stage[k] & (BSZ - 1)], 1);
  __syncthreads();
  int node = b * BSZ + tid;
  if (tid < BSZ && node < N_NODES) {
    float di = rsqrtf((float)(cnt[tid] + 1));     // +1 self-loop; always > 0
    dinv[node] = di;
#pragma unroll
    for (int c = 0; c < 5; c++) xd[node * 5 + c] = x[node * 5 + c] * di;
  }
}

// ---------- layer-1 aggregation (5-dim, L2-resident table) + fused MLP ----------
__global__ void k_agg1(const unsigned* __restrict__ stage, const int* __restrict__ boffs,
                       const float* __restrict__ xd, const float* __restrict__ dinv,
                       const float* __restrict__ W1, const float* __restrict__ b1,
                       const float* __restrict__ W2, float* __restrict__ g2) {
  __shared__ float acc[BSZ * 5];
  __shared__ float w1[150], bb1[30], w2[240];
  int b = blockIdx.x, tid = threadIdx.x;
  for (int i = tid; i < BSZ * 5; i += 256) acc[i] = 0.f;
  for (int i = tid; i < 150; i += 256) w1[i] = W1[i];
  for (int i = tid; i < 30; i += 256) bb1[i] = b1[i];
  for (int i = tid; i < 240; i += 256) w2[i] = W2[i];
  __syncthreads();
  int beg = boffs[b], end = boffs[b + 1];
  int group = tid / 5, lane = tid - group * 5;    // 51 groups x 5 lanes, tid 255 idle
  if (tid < 255) {
    int k = beg + group;
    if (k < end) {
      unsigned v = stage[k];                       // depth-2 stage pipeline
      for (k += 51; k < end; k += 51) {
        unsigned vn = stage[k];
        int s = v >> BSH, l = v & (BSZ - 1);
        atomAddF(&acc[l * 5 + lane], xd[s * 5 + lane]);
        v = vn;
      }
      int s = v >> BSH, l = v & (BSZ - 1);
      atomAddF(&acc[l * 5 + lane], xd[s * 5 + lane]);
    }
  }
  __syncthreads();
  int node = b * BSZ + tid;
  if (tid < BSZ && node < N_NODES) {
    float di = dinv[node];
    float t[5];
#pragma unroll
    for (int c = 0; c < 5; c++) t[c] = (acc[tid * 5 + c] + xd[node * 5 + c]) * di;
    float h[30];
#pragma unroll
    for (int j = 0; j < 30; j++) h[j] = bb1[j];
#pragma unroll
    for (int k = 0; k < 5; k++)
#pragma unroll
      for (int j = 0; j < 30; j++) h[j] += t[k] * w1[k * 30 + j];
    float g[8] = {0, 0, 0, 0, 0, 0, 0, 0};
#pragma unroll
    for (int j = 0; j < 30; j++) {
      float hj = fmaxf(h[j], 0.f);
#pragma unroll
      for (int c = 0; c < 8; c++) g[c] += hj * w2[j * 8 + c];
    }
    float4* gv = (float4*)g2;
    gv[node * 2]     = make_float4(g[0] * di, g[1] * di, g[2] * di, g[3] * di);
    gv[node * 2 + 1] = make_float4(g[4] * di, g[5] * di, g[6] * di, g[7] * di);
  }
}

// ---------- layer-2 aggregation (8-dim, L2-resident table) + fused pooling ----------
__global__ void k_agg2(const unsigned* __restrict__ stage, const int* __restrict__ boffs,
                       const float* __restrict__ g2, const float* __restrict__ dinv,
                       const float* __restrict__ b2, const int* __restrict__ batch,
                       float* __restrict__ gsum) {
  __shared__ float acc[BSZ * 8];
  __shared__ float gpool[BSZ * 8];
  __shared__ float bb2[8];
  __shared__ int batch0s;
  int b = blockIdx.x, tid = threadIdx.x;
  for (int i = tid; i < BSZ * 8; i += 256) { acc[i] = 0.f; gpool[i] = 0.f; }
  if (tid < 8) bb2[tid] = b2[tid];
  if (tid == 0) batch0s = batch[b * BSZ];
  __syncthreads();
  int beg = boffs[b], end = boffs[b + 1];
  int group = tid >> 3, lane = tid & 7;           // 32 groups x 8 lanes
  int k = beg + group;
  if (k < end) {
    unsigned v = stage[k];                         // depth-2 stage pipeline
    for (k += 32; k < end; k += 32) {
      unsigned vn = stage[k];
      int s = v >> BSH, l = v & (BSZ - 1);
      atomAddF(&acc[l * 8 + lane], g2[s * 8 + lane]);
      v = vn;
    }
    int s = v >> BSH, l = v & (BSZ - 1);
    atomAddF(&acc[l * 8 + lane], g2[s * 8 + lane]);
  }
  __syncthreads();
  int node = b * BSZ + tid;
  int batch0 = batch0s;
  if (tid < BSZ && node < N_NODES) {
    float di = dinv[node];
    int goff = batch[node] - batch0;
#pragma unroll
    for (int c = 0; c < 8; c++) {
      float val = di * (g2[node * 8 + c] + acc[tid * 8 + c]) + bb2[c];
      if (goff < BSZ) atomAddF(&gpool[goff * 8 + c], val);
      else            atomAddF(&gsum[batch[node] * 8 + c], val);
    }
  }
  __syncthreads();
  for (int i = tid; i < BSZ * 8; i += 256) {
    int gid = batch0 + (i >> 3);
    float v = gpool[i];
    if (gid < N_GRAPHS && v != 0.f) atomAddF(&gsum[gid * 8 + (i & 7)], v);
  }
}

// ---------- epilogue: divide by per-graph node count (binary search, batch sorted) ----------
__global__ void k_final(const float* __restrict__ gsum, const int* __restrict__ batch,
                        float* __restrict__ out) {
  int i = blockIdx.x * 256 + threadIdx.x;
  if (i >= N_GRAPHS * 8) return;
  int g = i >> 3;
  int lo = 0, hi = N_NODES;
  while (lo < hi) { int m = (lo + hi) >> 1; if (batch[m] < g) lo = m + 1; else hi = m; }
  int lo2 = lo, hi2 = N_NODES;
  while (lo2 < hi2) { int m = (lo2 + hi2) >> 1; if (batch[m] <= g) lo2 = m + 1; else hi2 = m; }
  float c = (float)(lo2 - lo);
  out[i] = gsum[i] / fmaxf(c, 1.f);
}

extern "C" void kernel_launch(void* const* d_in, const int* in_sizes, int n_in,
                              void* d_out, int out_size, void* d_ws, size_t ws_size,
                              hipStream_t stream) {
  const float* x    = (const float*)d_in[0];
  const int* ei     = (const int*)d_in[1];
  const int* batch  = (const int*)d_in[2];
  const float* W1   = (const float*)d_in[3];
  const float* b1   = (const float*)d_in[4];
  const float* W2   = (const float*)d_in[5];
  const float* b2   = (const float*)d_in[6];
  const int* srcp = ei;
  const int* dstp = ei + N_EDGES;
  float* out = (float*)d_out;

  // workspace carve (~22 MB)
  char* base = (char*)d_ws;
  size_t o = 0;
  auto carve = [&](size_t bytes) -> char* {
    char* p = base + o;
    o += (bytes + 255) & ~(size_t)255;
    return p;
  };
  int* bcnt       = (int*)carve((size_t)NB * 4);
  int* boffs      = (int*)carve((size_t)(NB + 1) * 4);
  int* blockBase  = (int*)carve((size_t)FILL_BLOCKS * NB * 4);
  unsigned* stage = (unsigned*)carve((size_t)N_EDGES * 4);
  float* dinv     = (float*)carve((size_t)N_NODES * 4);
  float* xd       = (float*)carve((size_t)N_NODES * 5 * 4);
  float* g2       = (float*)carve((size_t)N_NODES * 8 * 4);
  float* gsum     = (float*)carve((size_t)N_GRAPHS * 8 * 4);

  hipMemsetAsync(bcnt, 0, (size_t)NB * 4, stream);
  hipMemsetAsync(gsum, 0, (size_t)N_GRAPHS * 8 * 4, stream);

  k_count<<<FILL_BLOCKS, 256, 0, stream>>>(dstp, bcnt, blockBase);
  k_bscan<<<1, 512, 0, stream>>>(bcnt, boffs);
  k_fill<<<FILL_BLOCKS, 256, 0, stream>>>(srcp, dstp, boffs, blockBase, stage);
  k_prep<<<NB, 256, 0, stream>>>(stage, boffs, x, dinv, xd);
  k_agg1<<<NB, 256, 0, stream>>>(stage, boffs, xd, dinv, W1, b1, W2, g2);
  k_agg2<<<NB, 256, 0, stream>>>(stage, boffs, g2, dinv, b2, batch, gsum);
  k_final<<<64, 256, 0, stream>>>(gsum, batch, out);
}